// Round 8
// baseline (1450.257 us; speedup 1.0000x reference)
//
#include <hip/hip_runtime.h>
#include <math.h>

#define B_ROWS 1024
#define NCAND  100000
#define DIN    128
#define DM     256
#define DBK    512
#define CAP    1024
#define DELTA  16.0f
#define DNBLK  98      /* dist n-splits: 98*1024 >= 100000 */
#define VGRID  2048    /* persistent blocks for values_tile */

typedef unsigned int  u32;
typedef unsigned short u16;
typedef _Float16 f16;
typedef __bf16 bfrag  __attribute__((ext_vector_type(8)));
typedef f16    hfrag  __attribute__((ext_vector_type(8)));
typedef u16    u16x8  __attribute__((ext_vector_type(8)));
typedef float  f32x16 __attribute__((ext_vector_type(16)));

#define MFMAB(a, b, c) __builtin_amdgcn_mfma_f32_32x32x16_bf16(a, b, c, 0, 0, 0)
#define MFMAH(a, b, c) __builtin_amdgcn_mfma_f32_32x32x16_f16(a, b, c, 0, 0, 0)

__device__ __forceinline__ u16 bf_hi(float v) { return (u16)(__float_as_uint(v) >> 16); }
__device__ __forceinline__ u16 bf_lo(float v) {
  float r = v - __uint_as_float(__float_as_uint(v) & 0xffff0000u);
  return (u16)(__float_as_uint(r) >> 16);
}
__device__ __forceinline__ float dec2(u16 h, u16 l) {
  return __uint_as_float((u32)h << 16) + __uint_as_float((u32)l << 16);
}
__device__ __forceinline__ u16 f2bf_rne(float v) {
  u32 b = __float_as_uint(v);
  return (u16)((b + 0x7fffu + ((b >> 16) & 1u)) >> 16);
}

__global__ void init_kernel(int* cnt) {
  int i = blockIdx.x * 256 + threadIdx.x;
  if (i < B_ROWS) cnt[i] = 0;
}
__global__ void diag_kernel(float* out, float v) {
  int i = blockIdx.x * 256 + threadIdx.x;
  if (i < B_ROWS) out[i] = v;
}
__global__ void zero_f(float* p) {
  p[(long)blockIdx.x * 256 + threadIdx.x] = 0.f;
}

// weight transforms, one launch.
#define SEG0 32768L
#define SEG1 131072L
#define SEG2 131072L
#define SEG3 65536L
#define SEG4 131072L
#define SEG5 131072L
#define SEG6 32768L
#define SEG7 131072L
#define SEG8 131072L
#define SEG9 65536L
__global__ void prep_weights(const float* __restrict__ lin_w, const float* __restrict__ b0w1,
                             const float* __restrict__ b0w2, const float* __restrict__ Kw,
                             const float* __restrict__ Tw1, const float* __restrict__ Tw2,
                             u16* __restrict__ linTh, u16* __restrict__ linTl,
                             u16* __restrict__ w1Th, u16* __restrict__ w1Tl,
                             u16* __restrict__ w2Th, u16* __restrict__ w2Tl,
                             u16* __restrict__ KwTh, u16* __restrict__ KwTl,
                             u16* __restrict__ T1T, u16* __restrict__ T2T,
                             f16* __restrict__ linH, f16* __restrict__ w1H,
                             f16* __restrict__ w2H, f16* __restrict__ KwH) {
  long id = (long)blockIdx.x * 256 + threadIdx.x;
  if (id < SEG0) { long k = id / DM, n = id % DM; float v = lin_w[id];
    linTh[n * DIN + k] = bf_hi(v); linTl[n * DIN + k] = bf_lo(v); return; } id -= SEG0;
  if (id < SEG1) { long k = id / DBK, n = id % DBK; float v = b0w1[id];
    w1Th[n * DM + k] = bf_hi(v); w1Tl[n * DM + k] = bf_lo(v); return; } id -= SEG1;
  if (id < SEG2) { long k = id / DM, n = id % DM; float v = b0w2[id];
    w2Th[n * DBK + k] = bf_hi(v); w2Tl[n * DBK + k] = bf_lo(v); return; } id -= SEG2;
  if (id < SEG3) { long k = id / DM, n = id % DM; float v = Kw[id];
    KwTh[n * DM + k] = bf_hi(v); KwTl[n * DM + k] = bf_lo(v); return; } id -= SEG3;
  if (id < SEG4) { long k = id / DBK, n = id % DBK; T1T[n * DM + k] = f2bf_rne(Tw1[id]); return; } id -= SEG4;
  if (id < SEG5) { long k = id / DM, n = id % DM; T2T[n * DBK + k] = f2bf_rne(Tw2[id]); return; } id -= SEG5;
  if (id < SEG6) { long k = id / DM, n = id % DM; linH[n * DIN + k] = (f16)lin_w[id]; return; } id -= SEG6;
  if (id < SEG7) { long k = id / DBK, n = id % DBK; w1H[n * DM + k] = (f16)b0w1[id]; return; } id -= SEG7;
  if (id < SEG8) { long k = id / DM, n = id % DM; w2H[n * DBK + k] = (f16)b0w2[id]; return; } id -= SEG8;
  if (id < SEG9) { long k = id / DM, n = id % DM; KwH[n * DM + k] = (f16)Kw[id]; }
}

// ---------- batch encode: split-bf16 3-term (precision path, M=1024 only) ----------
template <int RELU, int HAS_RES, int ASRC, int WPL, int WF32, int WHALF>
__global__ __launch_bounds__(256) void mfma_nt(
    const u16* __restrict__ Ah, const u16* __restrict__ Al, const float* __restrict__ Af,
    const u16* __restrict__ Bth, const u16* __restrict__ Btl,
    const float* __restrict__ bias,
    const u16* __restrict__ Rh, const u16* __restrict__ Rl,
    u16* __restrict__ Ch, u16* __restrict__ Cl, float* __restrict__ Cf, f16* __restrict__ Chf,
    int M, int K, int N) {
  const int tid = threadIdx.x;
  const int w = tid >> 6, lane = tid & 63;
  const int half = lane >> 5, l31 = lane & 31;
  const int bm = blockIdx.x * 128;
  const int bn = blockIdx.y * 128 + w * 32;
  const int koff = half * 8;
  f32x16 acc[4] = {};
  long arow[4];
#pragma unroll
  for (int i = 0; i < 4; i++) {
    int gm = bm + i * 32 + l31; if (gm > M - 1) gm = M - 1;
    arow[i] = (long)gm * K;
  }
  const long brow = (long)(bn + l31) * K;
  bfrag ah0[4], al0[4], bh0, bl0, ah1[4], al1[4], bh1, bl1;
  auto lda = [&](int i, int k, bfrag& dh, bfrag& dl) {
    if constexpr (ASRC == 1) {
      float4 f0 = *(const float4*)(Af + arow[i] + k + koff);
      float4 f1 = *(const float4*)(Af + arow[i] + k + koff + 4);
      float fv[8] = {f0.x, f0.y, f0.z, f0.w, f1.x, f1.y, f1.z, f1.w};
      u16x8 hh, ll;
#pragma unroll
      for (int e = 0; e < 8; e++) { hh[e] = bf_hi(fv[e]); ll[e] = bf_lo(fv[e]); }
      dh = __builtin_bit_cast(bfrag, hh); dl = __builtin_bit_cast(bfrag, ll);
    } else {
      dh = *(const bfrag*)(Ah + arow[i] + k + koff);
      dl = *(const bfrag*)(Al + arow[i] + k + koff);
    }
  };
  auto ldb = [&](int k, bfrag& dh, bfrag& dl) {
    dh = *(const bfrag*)(Bth + brow + k + koff);
    dl = *(const bfrag*)(Btl + brow + k + koff);
  };
#pragma unroll
  for (int i = 0; i < 4; i++) lda(i, 0, ah0[i], al0[i]);
  ldb(0, bh0, bl0);
  for (int k0 = 0; k0 < K; k0 += 16) {
    int kn = k0 + 16;
    int kp = (ASRC == 1) ? (kn < K ? kn : k0) : kn;
    ldb(kp, bh1, bl1);
#pragma unroll
    for (int i = 0; i < 4; i++) lda(i, kp, ah1[i], al1[i]);
#pragma unroll
    for (int i = 0; i < 4; i++) {
      acc[i] = MFMAB(ah0[i], bh0, acc[i]);
      acc[i] = MFMAB(ah0[i], bl0, acc[i]);
      acc[i] = MFMAB(al0[i], bh0, acc[i]);
    }
    bh0 = bh1; bl0 = bl1;
#pragma unroll
    for (int i = 0; i < 4; i++) { ah0[i] = ah1[i]; al0[i] = al1[i]; }
  }
  const int n = bn + l31;
  const float bi = bias ? bias[n] : 0.f;
#pragma unroll
  for (int i = 0; i < 4; i++) {
#pragma unroll
    for (int r = 0; r < 16; r++) {
      int row = (r & 3) + 8 * (r >> 2) + 4 * half;
      int gm = bm + i * 32 + row;
      if (gm < M) {
        float c = acc[i][r] + bi;
        long idx = (long)gm * N + n;
        if constexpr (HAS_RES) c += dec2(Rh[idx], Rl[idx]);
        if constexpr (RELU) c = fmaxf(c, 0.f);
        if constexpr (WPL) { Ch[idx] = bf_hi(c); Cl[idx] = bf_lo(c); }
        if constexpr (WF32) Cf[idx] = c;
        if constexpr (WHALF) Chf[idx] = (f16)c;
      }
    }
  }
}

// ---------- candidate encode: weight-stationary streamed f16 GEMM ----------
// C[M,N] = act(A[M,K] @ Bt[N,K]^T + bias)(+R). Wave holds its 32 n-cols' weights in
// registers (K/16 hfrags). Activations stream through LDS in 32-row tiles (coalesced
// uint4 staging, register-prefetch double buffer — the mfma_dist2 pattern).
// ASRC=1: A is fp32, converted during staging. MT=16 tiles (512 rows) per block.
#define WSMT 16
template <int K, int RELU, int HAS_RES, int ASRC>
__global__ __launch_bounds__(256) void gemm_ws(
    const f16* __restrict__ A, const float* __restrict__ Af,
    const f16* __restrict__ Bt, const float* __restrict__ bias,
    const f16* __restrict__ R, f16* __restrict__ C, int M, int N) {
  constexpr int KP  = K + 8;      // padded row (halves): row stride ≡ 4 mod 32 dwords
  constexpr int NLD = K / 64;     // uint4 (or 8-half groups) per thread per 32-row tile
  constexpr int KR  = K / 8;      // 8-half groups per row
  const int tid = threadIdx.x;
  const int w = tid >> 6, lane = tid & 63;
  const int half = lane >> 5, l31 = lane & 31;
  const long m0 = (long)blockIdx.x * (32 * WSMT);
  const int bn = blockIdx.y * 128 + w * 32;
  __shared__ u16 Bl[2][32][KP];
  // stationary weights for this wave's 32 n-cols
  hfrag wreg[K / 16];
  {
    const f16* wrow = Bt + (long)(bn + l31) * K + half * 8;
#pragma unroll
    for (int kk = 0; kk < K / 16; kk++) wreg[kk] = *(const hfrag*)(wrow + kk * 16);
  }
  const float bi = bias ? bias[bn + l31] : 0.f;
  uint4 pv[NLD]; float4 pf0[NLD], pf1[NLD];
  auto fetch = [&](long tile0) {
#pragma unroll
    for (int i = 0; i < NLD; i++) {
      int c = i * 256 + tid;
      long r = tile0 + (c / KR); if (r > (long)M - 1) r = M - 1;
      long off = r * K + (long)(c % KR) * 8;
      if constexpr (ASRC == 0) pv[i] = *(const uint4*)(A + off);
      else { pf0[i] = *(const float4*)(Af + off); pf1[i] = *(const float4*)(Af + off + 4); }
    }
  };
  auto commit = [&](int buf) {
#pragma unroll
    for (int i = 0; i < NLD; i++) {
      int c = i * 256 + tid;
      int r = c / KR, c8 = c % KR;
      if constexpr (ASRC == 0) *(uint4*)&Bl[buf][r][c8 * 8] = pv[i];
      else {
        hfrag h;
        h[0] = (f16)pf0[i].x; h[1] = (f16)pf0[i].y; h[2] = (f16)pf0[i].z; h[3] = (f16)pf0[i].w;
        h[4] = (f16)pf1[i].x; h[5] = (f16)pf1[i].y; h[6] = (f16)pf1[i].z; h[7] = (f16)pf1[i].w;
        *(hfrag*)&Bl[buf][r][c8 * 8] = h;
      }
    }
  };
  fetch(m0);
  commit(0);
  __syncthreads();
  for (int t = 0; t < WSMT; t++) {
    const long tm = m0 + (long)t * 32;
    if (tm >= M) break;                       // block-uniform
    const int buf = t & 1;
    const bool more = (t + 1 < WSMT) && (tm + 32 < M);
    if (more) fetch(tm + 32);
    // 2 interleaved accumulators to break the MFMA RAW chain
    f32x16 acc0 = {}, acc1 = {};
#pragma unroll
    for (int kk = 0; kk < K / 16; kk += 2) {
      hfrag a0 = *(const hfrag*)&Bl[buf][l31][kk * 16 + half * 8];
      hfrag a1 = *(const hfrag*)&Bl[buf][l31][(kk + 1) * 16 + half * 8];
      acc0 = MFMAH(a0, wreg[kk], acc0);
      acc1 = MFMAH(a1, wreg[kk + 1], acc1);
    }
    acc0 = acc0 + acc1;
    const int n = bn + l31;
#pragma unroll
    for (int r = 0; r < 16; r++) {
      int row = (r & 3) + 8 * (r >> 2) + 4 * half;
      long gm = tm + row;
      if (gm < M) {
        float c = acc0[r] + bi;
        long idx = gm * N + n;
        if constexpr (HAS_RES) c += (float)R[idx];
        if constexpr (RELU) c = fmaxf(c, 0.f);
        C[idx] = (f16)c;
      }
    }
    if (more) commit(buf ^ 1);
    __syncthreads();
  }
}

// LayerNorm f16 in/out, fp32 math, one row per WAVE
__global__ void ln_h(const f16* __restrict__ in, f16* __restrict__ out,
                     const float* __restrict__ g, const float* __restrict__ b, int M) {
  const int w = threadIdx.x >> 6, l = threadIdx.x & 63;
  const int r = blockIdx.x * 4 + w;
  if (r >= M) return;
  const f16* row = in + (long)r * DM;
  float v[4]; float s = 0.f, q = 0.f;
#pragma unroll
  for (int c = 0; c < 4; c++) { v[c] = (float)row[l + c * 64]; s += v[c]; q += v[c] * v[c]; }
  for (int o = 32; o; o >>= 1) { s += __shfl_xor(s, o); q += __shfl_xor(q, o); }
  float mean = s * (1.f / 256.f);
  float var = q * (1.f / 256.f) - mean * mean;
  float rs = rsqrtf(var + 1e-5f);
  f16* orow = out + (long)r * DM;
#pragma unroll
  for (int c = 0; c < 4; c++)
    orow[l + c * 64] = (f16)((v[c] - mean) * rs * g[l + c * 64] + b[l + c * 64]);
}

// dist: s[m][n] = cnorm[n] - 2*dot(kb[m], ck[n]) in fp16 MFMA.
#define DNT 32
#define DNTILES 32
template <int MODE>
__global__ __launch_bounds__(256) void mfma_dist2(
    const f16* __restrict__ Ah, const f16* __restrict__ Bh,
    const float* __restrict__ cnorm, float* __restrict__ partial,
    const float* __restrict__ minf, int* __restrict__ cnt, int* __restrict__ listI) {
  const int tid = threadIdx.x;
  const int w = tid >> 6, lane = tid & 63;
  const int half = lane >> 5, l31 = lane & 31;
  const int bm = blockIdx.x * 128;
  const long bn0 = (long)blockIdx.y * (DNT * DNTILES);
  const int STEP = (MODE == 0) ? 4 : 1;
  __shared__ u16 Bl[2][DNT][264];
  hfrag areg[16];
  {
    const hfrag* arow = (const hfrag*)(Ah + (long)(bm + w * 32 + l31) * DM);
#pragma unroll
    for (int kk = 0; kk < 16; kk++) areg[kk] = arow[kk * 2 + half];
  }
  float runmin[16], thr[16];
  if constexpr (MODE == 0) {
#pragma unroll
    for (int r = 0; r < 16; r++) runmin[r] = 3.4e38f;
  } else {
#pragma unroll
    for (int r = 0; r < 16; r++) {
      int row = (r & 3) + 8 * (r >> 2) + 4 * half;
      thr[r] = minf[bm + w * 32 + row] + DELTA;
    }
  }
#pragma unroll
  for (int i = 0; i < 4; i++) {
    int c = i * 256 + tid, row = c >> 5, col8 = c & 31;
    long gn = bn0 + row; if (gn >= NCAND) gn = NCAND - 1;
    *(uint4*)&Bl[0][row][col8 * 8] = *(const uint4*)(Bh + gn * DM + col8 * 8);
  }
  __syncthreads();
  int pi = 0;
  for (int nt = 0; nt < DNTILES; nt += STEP, pi++) {
    const int buf = pi & 1;
    uint4 v[4];
    const bool more = (nt + STEP) < DNTILES;
    if (more) {
      long base = bn0 + (long)(nt + STEP) * DNT;
#pragma unroll
      for (int i = 0; i < 4; i++) {
        int c = i * 256 + tid;
        long g = base + (c >> 5); if (g >= NCAND) g = NCAND - 1;
        v[i] = *(const uint4*)(Bh + g * DM + (c & 31) * 8);
      }
    }
    f32x16 acc0 = {}, acc1 = {};
#pragma unroll
    for (int kk = 0; kk < 16; kk += 2) {
      hfrag b0 = *(const hfrag*)&Bl[buf][l31][kk * 16 + half * 8];
      hfrag b1 = *(const hfrag*)&Bl[buf][l31][(kk + 1) * 16 + half * 8];
      acc0 = MFMAH(areg[kk], b0, acc0);
      acc1 = MFMAH(areg[kk + 1], b1, acc1);
    }
    acc0 = acc0 + acc1;
    long n = bn0 + (long)nt * DNT + l31;
    bool nok = n < NCAND;
    float cn = nok ? cnorm[n] : 0.f;
    if constexpr (MODE == 0) {
#pragma unroll
      for (int r = 0; r < 16; r++) {
        float s = nok ? cn - 2.f * acc0[r] : 3.4e38f;
        runmin[r] = fminf(runmin[r], s);
      }
    } else {
      if (nok) {
#pragma unroll
        for (int r = 0; r < 16; r++) {
          float s = cn - 2.f * acc0[r];
          if (s <= thr[r]) {
            int row = (r & 3) + 8 * (r >> 2) + 4 * half;
            int m = bm + w * 32 + row;
            int p = atomicAdd(&cnt[m], 1);
            if (p < CAP) listI[(long)m * CAP + p] = (int)n;
          }
        }
      }
    }
    if (more) {
#pragma unroll
      for (int i = 0; i < 4; i++) {
        int c = i * 256 + tid;
        *(uint4*)&Bl[buf ^ 1][c >> 5][(c & 31) * 8] = v[i];
      }
    }
    __syncthreads();
  }
  if constexpr (MODE == 0) {
#pragma unroll
    for (int r = 0; r < 16; r++) {
      float s = runmin[r];
      s = fminf(s, __shfl_xor(s, 1));  s = fminf(s, __shfl_xor(s, 2));
      s = fminf(s, __shfl_xor(s, 4));  s = fminf(s, __shfl_xor(s, 8));
      s = fminf(s, __shfl_xor(s, 16));
      if (l31 == 0) {
        int row = (r & 3) + 8 * (r >> 2) + 4 * half;
        partial[(long)blockIdx.y * B_ROWS + bm + w * 32 + row] = s;
      }
    }
  }
}

__global__ void dist_reduce(const float* __restrict__ partial, float* __restrict__ minf) {
  int m = blockIdx.x * 256 + threadIdx.x;
  float v = 3.4e38f;
  for (int j = 0; j < DNBLK; j++) v = fminf(v, partial[(long)j * B_ROWS + m]);
  minf[m] = v;
}

// LayerNorm over 256, split-bf16 planes in/out (batch path)
__global__ void ln_split(const u16* __restrict__ inh, const u16* __restrict__ inl,
                         u16* __restrict__ outh, u16* __restrict__ outl,
                         const float* __restrict__ g, const float* __restrict__ b) {
  const int r = blockIdx.x, t = threadIdx.x;
  const int w = t >> 6, l = t & 63;
  float v = dec2(inh[(long)r * DM + t], inl[(long)r * DM + t]);
  float s = v, q = v * v;
  for (int o = 32; o; o >>= 1) { s += __shfl_xor(s, o); q += __shfl_xor(q, o); }
  __shared__ float ps[4], pq[4];
  if (!l) { ps[w] = s; pq[w] = q; }
  __syncthreads();
  float S = ps[0] + ps[1] + ps[2] + ps[3];
  float Q = pq[0] + pq[1] + pq[2] + pq[3];
  float mean = S * (1.f / 256.f);
  float var = Q * (1.f / 256.f) - mean * mean;
  float rs = rsqrtf(var + 1e-5f);
  float o2 = (v - mean) * rs * g[t] + b[t];
  outh[(long)r * DM + t] = bf_hi(o2);
  outl[(long)r * DM + t] = bf_lo(o2);
}

__global__ void rownorm_h(const f16* __restrict__ X, float* __restrict__ out) {
  const int w = threadIdx.x >> 6, l = threadIdx.x & 63;
  const int r = blockIdx.x * 4 + w;
  if (r >= NCAND) return;
  const f16* row = X + (long)r * DM;
  float s = 0.f;
  for (int i = l; i < DM; i += 64) { float v = (float)row[i]; s += v * v; }
  for (int o = 32; o; o >>= 1) s += __shfl_xor(s, o);
  if (!l) out[r] = s;
}

// ||kb[r]||^2 for batch rows (fp32)
__global__ void rownorm_f(const float* __restrict__ X, float* __restrict__ out) {
  const int w = threadIdx.x >> 6, l = threadIdx.x & 63;
  const int r = blockIdx.x * 4 + w;
  if (r >= B_ROWS) return;
  const float* row = X + (long)r * DM;
  float s = 0.f;
  for (int i = l; i < DM; i += 64) { float v = row[i]; s += v * v; }
  for (int o = 32; o; o >>= 1) s += __shfl_xor(s, o);
  if (!l) out[r] = s;
}

// Tile list build: one block, 1024 threads. Tiles of 32 pairs never span rows.
__global__ void scan_tiles(const int* __restrict__ cnt, int* __restrict__ tileRow,
                           int* __restrict__ tileOff, int* __restrict__ nTiles,
                           float* __restrict__ Z, float* __restrict__ ZY) {
  const int m = threadIdx.x;
  int c = cnt[m]; if (c > CAP) c = CAP;
  int nt = (c + 31) >> 5;
  __shared__ int s[B_ROWS];
  s[m] = nt;
  __syncthreads();
  for (int off2 = 1; off2 < B_ROWS; off2 <<= 1) {
    int add = (m >= off2) ? s[m - off2] : 0;
    __syncthreads();
    s[m] += add;
    __syncthreads();
  }
  int end = s[m], base = end - nt;
  if (m == B_ROWS - 1) nTiles[0] = end;
  for (int j = 0; j < nt; j++) { tileRow[base + j] = m; tileOff[base + j] = j * 32; }
  Z[m] = 0.f; ZY[m] = 0.f;
}

// Tile-parallel values: persistent blocks stride over (row, 32-pair) tiles.
#define VT 32
__global__ __launch_bounds__(256) void values_tile(
    const float* __restrict__ Kb, const f16* __restrict__ Ck,
    const float* __restrict__ cy, const int* __restrict__ cnt,
    const int* __restrict__ listI, const float* __restrict__ minf,
    const float* __restrict__ knorm, const int* __restrict__ tileRow,
    const int* __restrict__ tileOff, const int* __restrict__ nTilesP,
    const u16* __restrict__ T1T, const float* __restrict__ Tb1,
    const u16* __restrict__ T2T,
    float* __restrict__ ctxAcc, float* __restrict__ Z, float* __restrict__ ZY) {
  const int t = threadIdx.x;
  const int w = t >> 6, lane = t & 63;
  const int half = lane >> 5, l31 = lane & 31;
  __shared__ float sk[256];
  __shared__ u16 U[VT][264];
  __shared__ u16 T1[VT][520];
  __shared__ float s2[VT], sw[VT];
  __shared__ int sidx[VT];
  __shared__ float sSW, sSWY;
  const int nTiles = nTilesP[0];
  for (int ti = blockIdx.x; ti < nTiles; ti += VGRID) {
    __syncthreads();
    const int m = tileRow[ti], j0 = tileOff[ti];
    int n = cnt[m]; if (n > CAP) n = CAP;
    const float gmin = minf[m];
    sk[t] = Kb[(long)m * DM + t];
    if (t < VT) {
      int j = j0 + t;
      sidx[t] = (j < n) ? listI[(long)m * CAP + j] : listI[(long)m * CAP];
    }
    __syncthreads();
    {
      float kc = sk[t];
#pragma unroll 4
      for (int r = 0; r < VT; r++)
        U[r][t] = f2bf_rne(kc - (float)Ck[(long)sidx[r] * DM + t]);
    }
    for (int rr = 0; rr < 8; rr++) {
      int r = w * 8 + rr;
      const f16* cr = Ck + (long)sidx[r] * DM;
      float a = 0.f;
      for (int c = lane; c < DM; c += 64) { float u = sk[c] - (float)cr[c]; a += u * u; }
      for (int o = 32; o; o >>= 1) a += __shfl_xor(a, o);
      if (!lane) s2[r] = a;
    }
    __syncthreads();
    if (w == 0) {
      float swv = 0.f, syv = 0.f;
      if (lane < VT) {
        int j = j0 + lane;
        swv = (j < n) ? expf(-(s2[lane] - knorm[m] - gmin)) : 0.f;
        syv = swv * cy[sidx[lane]];
        sw[lane] = swv;
      }
      for (int o = 16; o; o >>= 1) { swv += __shfl_xor(swv, o); syv += __shfl_xor(syv, o); }
      if (lane == 0) { sSW = swv; sSWY = syv; }
    }
    __syncthreads();
    {
      f32x16 acc[4] = {};
#pragma unroll 2
      for (int k0 = 0; k0 < DM; k0 += 16) {
        bfrag af = *(const bfrag*)&U[l31][k0 + half * 8];
#pragma unroll
        for (int nt2 = 0; nt2 < 4; nt2++) {
          int gn = w * 128 + nt2 * 32 + l31;
          bfrag bf = *(const bfrag*)&T1T[(long)gn * DM + k0 + half * 8];
          acc[nt2] = MFMAB(af, bf, acc[nt2]);
        }
      }
#pragma unroll
      for (int nt2 = 0; nt2 < 4; nt2++) {
        int gn = w * 128 + nt2 * 32 + l31;
        float bb = Tb1[gn];
#pragma unroll
        for (int r = 0; r < 16; r++) {
          int mr = (r & 3) + 8 * (r >> 2) + 4 * half;
          T1[mr][gn] = f2bf_rne(fmaxf(acc[nt2][r] + bb, 0.f));
        }
      }
    }
    __syncthreads();
    {
      f32x16 acc[2] = {};
#pragma unroll 2
      for (int k0 = 0; k0 < DBK; k0 += 16) {
        bfrag af = *(const bfrag*)&T1[l31][k0 + half * 8];
#pragma unroll
        for (int nt2 = 0; nt2 < 2; nt2++) {
          int gn = w * 64 + nt2 * 32 + l31;
          bfrag bf = *(const bfrag*)&T2T[(long)gn * DBK + k0 + half * 8];
          acc[nt2] = MFMAB(af, bf, acc[nt2]);
        }
      }
      float swr[16];
#pragma unroll
      for (int r = 0; r < 16; r++) swr[r] = sw[(r & 3) + 8 * (r >> 2) + 4 * half];
#pragma unroll
      for (int nt2 = 0; nt2 < 2; nt2++) {
        int gn = w * 64 + nt2 * 32 + l31;
        float p = 0.f;
#pragma unroll
        for (int r = 0; r < 16; r++) p += swr[r] * acc[nt2][r];
        p += __shfl_xor(p, 32);
        if (half == 0) atomicAdd(&ctxAcc[(long)m * DM + gn], p);
      }
      if (t == 0) { atomicAdd(&Z[m], sSW); atomicAdd(&ZY[m], sSWY); }
    }
  }
}

// x=xb+(ctxAcc+ZY*labw+Z*labb)/Z; x+=MLP(LN(x)); out=relu(LN(x))@hw+hb2. 4 rows/block.
__global__ void final_kernel(const float* __restrict__ xb, const float* __restrict__ ctxAcc,
                             const float* __restrict__ Z, const float* __restrict__ ZY,
                             const float* __restrict__ labw, const float* __restrict__ labb,
                             const float* __restrict__ pg, const float* __restrict__ pb,
                             const float* __restrict__ pw1, const float* __restrict__ pb1,
                             const float* __restrict__ pw2, const float* __restrict__ pb2,
                             const float* __restrict__ hg, const float* __restrict__ hb,
                             const float* __restrict__ hw, const float* __restrict__ hb2,
                             float* __restrict__ out) {
  const int b0 = blockIdx.x * 4, t = threadIdx.x;
  const int w = t >> 6, l = t & 63;
  __shared__ float sx[4][260], sln[4][260], sh[4][516], sx2[4][260];
  for (int e = t; e < 1024; e += 256) {
    int r = e >> 8, d = e & 255;
    int m = b0 + r;
    float zi = 1.f / Z[m];
    float ctx = (ctxAcc[(long)m * DM + d] + ZY[m] * labw[d] + Z[m] * labb[d]) * zi;
    sx[r][d] = xb[(long)m * DM + d] + ctx;
  }
  __syncthreads();
  {
    float s = 0.f, q = 0.f;
    for (int d = l; d < 256; d += 64) { float v = sx[w][d]; s += v; q += v * v; }
    for (int o = 32; o; o >>= 1) { s += __shfl_xor(s, o); q += __shfl_xor(q, o); }
    float mean = s * (1.f / 256.f), var = q * (1.f / 256.f) - mean * mean;
    float rs = rsqrtf(var + 1e-5f);
    for (int d = l; d < 256; d += 64) sln[w][d] = (sx[w][d] - mean) * rs * pg[d] + pb[d];
  }
  __syncthreads();
  {
    float acc[4][2] = {};
    for (int k = 0; k < 256; k++) {
      float w0 = pw1[(long)k * DBK + t], w1 = pw1[(long)k * DBK + t + 256];
#pragma unroll
      for (int r = 0; r < 4; r++) { float a = sln[r][k]; acc[r][0] += a * w0; acc[r][1] += a * w1; }
    }
#pragma unroll
    for (int r = 0; r < 4; r++) {
      sh[r][t] = fmaxf(acc[r][0] + pb1[t], 0.f);
      sh[r][t + 256] = fmaxf(acc[r][1] + pb1[t + 256], 0.f);
    }
  }
  __syncthreads();
  {
    float acc2[4] = {};
    for (int k = 0; k < 512; k++) {
      float wv = pw2[(long)k * DM + t];
#pragma unroll
      for (int r = 0; r < 4; r++) acc2[r] += sh[r][k] * wv;
    }
#pragma unroll
    for (int r = 0; r < 4; r++) sx2[r][t] = sx[r][t] + acc2[r] + pb2[t];
  }
  __syncthreads();
  {
    float s = 0.f, q = 0.f;
    for (int d = l; d < 256; d += 64) { float v = sx2[w][d]; s += v; q += v * v; }
    for (int o = 32; o; o >>= 1) { s += __shfl_xor(s, o); q += __shfl_xor(q, o); }
    float mean = s * (1.f / 256.f), var = q * (1.f / 256.f) - mean * mean;
    float rs = rsqrtf(var + 1e-5f);
    float dp = 0.f;
    for (int d = l; d < 256; d += 64) {
      float v = fmaxf((sx2[w][d] - mean) * rs * hg[d] + hb[d], 0.f);
      dp += v * hw[d];
    }
    for (int o = 32; o; o >>= 1) dp += __shfl_xor(dp, o);
    if (!l) out[b0 + w] = dp + hb2[0];
  }
}

extern "C" void kernel_launch(void* const* d_in, const int* in_sizes, int n_in,
                              void* d_out, int out_size, void* d_ws, size_t ws_size,
                              hipStream_t stream) {
  const float* x_num = (const float*)d_in[0];
  const float* cand  = (const float*)d_in[1];
  const float* cy    = (const float*)d_in[2];
  const float* lin_w = (const float*)d_in[4];
  const float* lin_b = (const float*)d_in[5];
  const float* b0w1  = (const float*)d_in[6];
  const float* b0b1  = (const float*)d_in[7];
  const float* b0w2  = (const float*)d_in[8];
  const float* b0b2  = (const float*)d_in[9];
  const float* mixg  = (const float*)d_in[10];
  const float* mixb  = (const float*)d_in[11];
  const float* Kw    = (const float*)d_in[12];
  const float* Kbias = (const float*)d_in[13];
  const float* labw  = (const float*)d_in[14];
  const float* labb  = (const float*)d_in[15];
  const float* Tw1   = (const float*)d_in[16];
  const float* Tb1   = (const float*)d_in[17];
  const float* Tw2   = (const float*)d_in[18];
  const float* pg    = (const float*)d_in[19];
  const float* pb    = (const float*)d_in[20];
  const float* pw1   = (const float*)d_in[21];
  const float* pb1   = (const float*)d_in[22];
  const float* pw2   = (const float*)d_in[23];
  const float* pb2   = (const float*)d_in[24];
  const float* hg    = (const float*)d_in[25];
  const float* hb    = (const float*)d_in[26];
  const float* hw    = (const float*)d_in[27];
  const float* hb2   = (const float*)d_in[28];
  float* out = (float*)d_out;

  char* ws = (char*)d_ws;
  size_t off = 0;
  auto alloc = [&](size_t bytes) -> void* {
    void* p = ws + off;
    off += (bytes + 255) & ~(size_t)255;
    return p;
  };
  f16*   ck_h    = (f16*)alloc((size_t)NCAND * DM * 2);
  float* cnorm   = (float*)alloc((size_t)NCAND * 4);
  float* partial = (float*)alloc((size_t)DNBLK * B_ROWS * 4);
  float* minf    = (float*)alloc((size_t)B_ROWS * 4);
  int*   cnt     = (int*)alloc((size_t)B_ROWS * 4);
  int*   listI   = (int*)alloc((size_t)B_ROWS * CAP * 4);
  float* xb      = (float*)alloc((size_t)B_ROWS * DM * 4);
  float* kb      = (float*)alloc((size_t)B_ROWS * DM * 4);
  f16*   kb_h    = (f16*)alloc((size_t)B_ROWS * DM * 2);
  float* ctxAcc  = (float*)alloc((size_t)B_ROWS * DM * 4);
  float* Z       = (float*)alloc((size_t)B_ROWS * 4);
  float* ZY      = (float*)alloc((size_t)B_ROWS * 4);
  float* knorm   = (float*)alloc((size_t)B_ROWS * 4);
  int*   tileRow = (int*)alloc((size_t)B_ROWS * 32 * 4);
  int*   tileOff = (int*)alloc((size_t)B_ROWS * 32 * 4);
  int*   nTiles  = (int*)alloc(256);
  u16* bx1h = (u16*)alloc((size_t)B_ROWS * DM * 2);
  u16* bx1l = (u16*)alloc((size_t)B_ROWS * DM * 2);
  u16* bhh  = (u16*)alloc((size_t)B_ROWS * DBK * 2);
  u16* bhl  = (u16*)alloc((size_t)B_ROWS * DBK * 2);
  u16* bx2h = (u16*)alloc((size_t)B_ROWS * DM * 2);
  u16* bx2l = (u16*)alloc((size_t)B_ROWS * DM * 2);
  u16* blnh = (u16*)alloc((size_t)B_ROWS * DM * 2);
  u16* blnl = (u16*)alloc((size_t)B_ROWS * DM * 2);
  u16* linTh = (u16*)alloc((size_t)DM * DIN * 2);
  u16* linTl = (u16*)alloc((size_t)DM * DIN * 2);
  u16* w1Th  = (u16*)alloc((size_t)DBK * DM * 2);
  u16* w1Tl  = (u16*)alloc((size_t)DBK * DM * 2);
  u16* w2Th  = (u16*)alloc((size_t)DM * DBK * 2);
  u16* w2Tl  = (u16*)alloc((size_t)DM * DBK * 2);
  u16* KwTh  = (u16*)alloc((size_t)DM * DM * 2);
  u16* KwTl  = (u16*)alloc((size_t)DM * DM * 2);
  u16* T1T   = (u16*)alloc((size_t)DBK * DM * 2);
  u16* T2T   = (u16*)alloc((size_t)DM * DBK * 2);
  f16* linH  = (f16*)alloc((size_t)DM * DIN * 2);
  f16* w1H   = (f16*)alloc((size_t)DBK * DM * 2);
  f16* w2H   = (f16*)alloc((size_t)DM * DBK * 2);
  f16* KwH   = (f16*)alloc((size_t)DM * DM * 2);
  size_t fixed_end = off;
  long chunk = 0;
  if (ws_size > fixed_end + 8192) {
    chunk = (long)((ws_size - fixed_end - 8192) / 2048);
    chunk -= chunk % 512;
    if (chunk > 100352) chunk = 100352;
  }
  if (chunk < 512) {
    diag_kernel<<<dim3(4), dim3(256), 0, stream>>>(out, (float)(ws_size >> 20));
    return;
  }
  f16* cx1 = (f16*)alloc((size_t)chunk * DM * 2);
  f16* chb = (f16*)alloc((size_t)chunk * DBK * 2);
  f16* cx2 = (f16*)alloc((size_t)chunk * DM * 2);

  prep_weights<<<dim3((unsigned)((SEG0+SEG1+SEG2+SEG3+SEG4+SEG5+SEG6+SEG7+SEG8+SEG9 + 255) / 256)),
                 dim3(256), 0, stream>>>(
      lin_w, b0w1, b0w2, Kw, Tw1, Tw2, linTh, linTl, w1Th, w1Tl, w2Th, w2Tl, KwTh, KwTl,
      T1T, T2T, linH, w1H, w2H, KwH);
  init_kernel<<<dim3(4), dim3(256), 0, stream>>>(cnt);
  zero_f<<<dim3(B_ROWS), dim3(256), 0, stream>>>(ctxAcc);

  // ---- batch encode (split-bf16 precision path) ----
  mfma_nt<0,0,1,1,0,0><<<dim3(8, 2), dim3(256), 0, stream>>>(
      nullptr, nullptr, x_num, linTh, linTl, lin_b, nullptr, nullptr,
      bx1h, bx1l, nullptr, nullptr, B_ROWS, DIN, DM);
  mfma_nt<1,0,0,1,0,0><<<dim3(8, 4), dim3(256), 0, stream>>>(
      bx1h, bx1l, nullptr, w1Th, w1Tl, b0b1, nullptr, nullptr,
      bhh, bhl, nullptr, nullptr, B_ROWS, DM, DBK);
  mfma_nt<0,1,0,1,1,0><<<dim3(8, 2), dim3(256), 0, stream>>>(
      bhh, bhl, nullptr, w2Th, w2Tl, b0b2, bx1h, bx1l,
      bx2h, bx2l, xb, nullptr, B_ROWS, DBK, DM);
  ln_split<<<dim3(B_ROWS), dim3(256), 0, stream>>>(bx2h, bx2l, blnh, blnl, mixg, mixb);
  mfma_nt<0,0,0,0,1,1><<<dim3(8, 2), dim3(256), 0, stream>>>(
      blnh, blnl, nullptr, KwTh, KwTl, Kbias, nullptr, nullptr,
      nullptr, nullptr, kb, kb_h, B_ROWS, DM, DM);
  rownorm_f<<<dim3(B_ROWS / 4), dim3(256), 0, stream>>>(kb, knorm);

  // ---- candidate encode (weight-stationary streamed f16 GEMMs) ----
  for (long o = 0; o < NCAND; o += chunk) {
    long m = NCAND - o; if (m > chunk) m = chunk;
    unsigned gx = (unsigned)((m + 511) / 512);
    gemm_ws<128,0,0,1><<<dim3(gx, 2), dim3(256), 0, stream>>>(
        nullptr, cand + o * DIN, linH, lin_b, nullptr, cx1, (int)m, DM);
    gemm_ws<256,1,0,0><<<dim3(gx, 4), dim3(256), 0, stream>>>(
        cx1, nullptr, w1H, b0b1, nullptr, chb, (int)m, DBK);
    gemm_ws<512,0,1,0><<<dim3(gx, 2), dim3(256), 0, stream>>>(
        chb, nullptr, w2H, b0b2, cx1, cx2, (int)m, DM);
    ln_h<<<dim3((unsigned)((m + 3) / 4)), dim3(256), 0, stream>>>(cx2, cx1, mixg, mixb, (int)m);
    gemm_ws<256,0,0,0><<<dim3(gx, 2), dim3(256), 0, stream>>>(
        cx1, nullptr, KwH, Kbias, nullptr, ck_h + o * DM, (int)m, DM);
  }
  rownorm_h<<<dim3(NCAND / 4), dim3(256), 0, stream>>>(ck_h, cnorm);

  // ---- neighbor window: sampled-min pass -> reduce -> compact pass ----
  mfma_dist2<0><<<dim3(8, DNBLK), dim3(256), 0, stream>>>(kb_h, ck_h, cnorm, partial, nullptr, nullptr, nullptr);
  dist_reduce<<<dim3(4), dim3(256), 0, stream>>>(partial, minf);
  mfma_dist2<1><<<dim3(8, DNBLK), dim3(256), 0, stream>>>(kb_h, ck_h, cnorm, nullptr, minf, cnt, listI);

  // ---- tile list + tile-parallel values ----
  scan_tiles<<<dim3(1), dim3(B_ROWS), 0, stream>>>(cnt, tileRow, tileOff, nTiles, Z, ZY);
  values_tile<<<dim3(VGRID), dim3(256), 0, stream>>>(kb, ck_h, cy, cnt, listI, minf, knorm,
                                                     tileRow, tileOff, nTiles,
                                                     T1T, Tb1, T2T, ctxAcc, Z, ZY);
  // ---- residual MLP + head ----
  final_kernel<<<dim3(B_ROWS / 4), dim3(256), 0, stream>>>(xb, ctxAcc, Z, ZY, labw, labb,
                                                           pg, pb, pw1, pb1, pw2, pb2,
                                                           hg, hb, hw, hb2, out);
}

// Round 9
// 1062.205 us; speedup vs baseline: 1.3653x; 1.3653x over previous
//
#include <hip/hip_runtime.h>
#include <math.h>

#define B_ROWS 1024
#define NCAND  100000
#define DIN    128
#define DM     256
#define DBK    512
#define CAP    1024
#define DELTA  16.0f
#define DNBLK  98      /* dist n-splits: 98*1024 >= 100000 */
#define VGRID  2048    /* persistent blocks for values_tile */

typedef unsigned int  u32;
typedef unsigned short u16;
typedef _Float16 f16;
typedef __bf16 bfrag  __attribute__((ext_vector_type(8)));
typedef f16    hfrag  __attribute__((ext_vector_type(8)));
typedef u16    u16x8  __attribute__((ext_vector_type(8)));
typedef float  f32x16 __attribute__((ext_vector_type(16)));

#define MFMAB(a, b, c) __builtin_amdgcn_mfma_f32_32x32x16_bf16(a, b, c, 0, 0, 0)
#define MFMAH(a, b, c) __builtin_amdgcn_mfma_f32_32x32x16_f16(a, b, c, 0, 0, 0)

__device__ __forceinline__ u16 bf_hi(float v) { return (u16)(__float_as_uint(v) >> 16); }
__device__ __forceinline__ u16 bf_lo(float v) {
  float r = v - __uint_as_float(__float_as_uint(v) & 0xffff0000u);
  return (u16)(__float_as_uint(r) >> 16);
}
__device__ __forceinline__ float dec2(u16 h, u16 l) {
  return __uint_as_float((u32)h << 16) + __uint_as_float((u32)l << 16);
}
__device__ __forceinline__ u16 f2bf_rne(float v) {
  u32 b = __float_as_uint(v);
  return (u16)((b + 0x7fffu + ((b >> 16) & 1u)) >> 16);
}

__global__ void init_kernel(int* cnt) {
  int i = blockIdx.x * 256 + threadIdx.x;
  if (i < B_ROWS) cnt[i] = 0;
}
__global__ void diag_kernel(float* out, float v) {
  int i = blockIdx.x * 256 + threadIdx.x;
  if (i < B_ROWS) out[i] = v;
}
__global__ void zero_f(float* p) {
  p[(long)blockIdx.x * 256 + threadIdx.x] = 0.f;
}

// weight transforms, one launch.
#define SEG0 32768L
#define SEG1 131072L
#define SEG2 131072L
#define SEG3 65536L
#define SEG4 131072L
#define SEG5 131072L
#define SEG6 32768L
#define SEG7 131072L
#define SEG8 131072L
#define SEG9 65536L
__global__ void prep_weights(const float* __restrict__ lin_w, const float* __restrict__ b0w1,
                             const float* __restrict__ b0w2, const float* __restrict__ Kw,
                             const float* __restrict__ Tw1, const float* __restrict__ Tw2,
                             u16* __restrict__ linTh, u16* __restrict__ linTl,
                             u16* __restrict__ w1Th, u16* __restrict__ w1Tl,
                             u16* __restrict__ w2Th, u16* __restrict__ w2Tl,
                             u16* __restrict__ KwTh, u16* __restrict__ KwTl,
                             u16* __restrict__ T1T, u16* __restrict__ T2T,
                             f16* __restrict__ linH, f16* __restrict__ w1H,
                             f16* __restrict__ w2H, f16* __restrict__ KwH) {
  long id = (long)blockIdx.x * 256 + threadIdx.x;
  if (id < SEG0) { long k = id / DM, n = id % DM; float v = lin_w[id];
    linTh[n * DIN + k] = bf_hi(v); linTl[n * DIN + k] = bf_lo(v); return; } id -= SEG0;
  if (id < SEG1) { long k = id / DBK, n = id % DBK; float v = b0w1[id];
    w1Th[n * DM + k] = bf_hi(v); w1Tl[n * DM + k] = bf_lo(v); return; } id -= SEG1;
  if (id < SEG2) { long k = id / DM, n = id % DM; float v = b0w2[id];
    w2Th[n * DBK + k] = bf_hi(v); w2Tl[n * DBK + k] = bf_lo(v); return; } id -= SEG2;
  if (id < SEG3) { long k = id / DM, n = id % DM; float v = Kw[id];
    KwTh[n * DM + k] = bf_hi(v); KwTl[n * DM + k] = bf_lo(v); return; } id -= SEG3;
  if (id < SEG4) { long k = id / DBK, n = id % DBK; T1T[n * DM + k] = f2bf_rne(Tw1[id]); return; } id -= SEG4;
  if (id < SEG5) { long k = id / DM, n = id % DM; T2T[n * DBK + k] = f2bf_rne(Tw2[id]); return; } id -= SEG5;
  if (id < SEG6) { long k = id / DM, n = id % DM; linH[n * DIN + k] = (f16)lin_w[id]; return; } id -= SEG6;
  if (id < SEG7) { long k = id / DBK, n = id % DBK; w1H[n * DM + k] = (f16)b0w1[id]; return; } id -= SEG7;
  if (id < SEG8) { long k = id / DM, n = id % DM; w2H[n * DBK + k] = (f16)b0w2[id]; return; } id -= SEG8;
  if (id < SEG9) { long k = id / DM, n = id % DM; KwH[n * DM + k] = (f16)Kw[id]; }
}

// ---------- batch encode: split-bf16 3-term (precision path, M=1024 only) ----------
template <int RELU, int HAS_RES, int ASRC, int WPL, int WF32, int WHALF>
__global__ __launch_bounds__(256) void mfma_nt(
    const u16* __restrict__ Ah, const u16* __restrict__ Al, const float* __restrict__ Af,
    const u16* __restrict__ Bth, const u16* __restrict__ Btl,
    const float* __restrict__ bias,
    const u16* __restrict__ Rh, const u16* __restrict__ Rl,
    u16* __restrict__ Ch, u16* __restrict__ Cl, float* __restrict__ Cf, f16* __restrict__ Chf,
    int M, int K, int N) {
  const int tid = threadIdx.x;
  const int w = tid >> 6, lane = tid & 63;
  const int half = lane >> 5, l31 = lane & 31;
  const int bm = blockIdx.x * 128;
  const int bn = blockIdx.y * 128 + w * 32;
  const int koff = half * 8;
  f32x16 acc[4] = {};
  long arow[4];
#pragma unroll
  for (int i = 0; i < 4; i++) {
    int gm = bm + i * 32 + l31; if (gm > M - 1) gm = M - 1;
    arow[i] = (long)gm * K;
  }
  const long brow = (long)(bn + l31) * K;
  bfrag ah0[4], al0[4], bh0, bl0, ah1[4], al1[4], bh1, bl1;
  auto lda = [&](int i, int k, bfrag& dh, bfrag& dl) {
    if constexpr (ASRC == 1) {
      float4 f0 = *(const float4*)(Af + arow[i] + k + koff);
      float4 f1 = *(const float4*)(Af + arow[i] + k + koff + 4);
      float fv[8] = {f0.x, f0.y, f0.z, f0.w, f1.x, f1.y, f1.z, f1.w};
      u16x8 hh, ll;
#pragma unroll
      for (int e = 0; e < 8; e++) { hh[e] = bf_hi(fv[e]); ll[e] = bf_lo(fv[e]); }
      dh = __builtin_bit_cast(bfrag, hh); dl = __builtin_bit_cast(bfrag, ll);
    } else {
      dh = *(const bfrag*)(Ah + arow[i] + k + koff);
      dl = *(const bfrag*)(Al + arow[i] + k + koff);
    }
  };
  auto ldb = [&](int k, bfrag& dh, bfrag& dl) {
    dh = *(const bfrag*)(Bth + brow + k + koff);
    dl = *(const bfrag*)(Btl + brow + k + koff);
  };
#pragma unroll
  for (int i = 0; i < 4; i++) lda(i, 0, ah0[i], al0[i]);
  ldb(0, bh0, bl0);
  for (int k0 = 0; k0 < K; k0 += 16) {
    int kn = k0 + 16;
    int kp = (ASRC == 1) ? (kn < K ? kn : k0) : kn;
    ldb(kp, bh1, bl1);
#pragma unroll
    for (int i = 0; i < 4; i++) lda(i, kp, ah1[i], al1[i]);
#pragma unroll
    for (int i = 0; i < 4; i++) {
      acc[i] = MFMAB(ah0[i], bh0, acc[i]);
      acc[i] = MFMAB(ah0[i], bl0, acc[i]);
      acc[i] = MFMAB(al0[i], bh0, acc[i]);
    }
    bh0 = bh1; bl0 = bl1;
#pragma unroll
    for (int i = 0; i < 4; i++) { ah0[i] = ah1[i]; al0[i] = al1[i]; }
  }
  const int n = bn + l31;
  const float bi = bias ? bias[n] : 0.f;
#pragma unroll
  for (int i = 0; i < 4; i++) {
#pragma unroll
    for (int r = 0; r < 16; r++) {
      int row = (r & 3) + 8 * (r >> 2) + 4 * half;
      int gm = bm + i * 32 + row;
      if (gm < M) {
        float c = acc[i][r] + bi;
        long idx = (long)gm * N + n;
        if constexpr (HAS_RES) c += dec2(Rh[idx], Rl[idx]);
        if constexpr (RELU) c = fmaxf(c, 0.f);
        if constexpr (WPL) { Ch[idx] = bf_hi(c); Cl[idx] = bf_lo(c); }
        if constexpr (WF32) Cf[idx] = c;
        if constexpr (WHALF) Chf[idx] = (f16)c;
      }
    }
  }
}

// ---------- candidate encode: classic LDS-tiled f16 GEMM ----------
// C[M,N] = act(A[M,K] @ Bt[N,K]^T + bias)(+R). 128x128 tile, BK=64, 256 threads.
// Both operands staged coalesced into LDS (72-half row stride: bank = 4*row+off,
// conflict-free b128 fragment reads); ASRC=1 converts fp32->f16 during staging.
template <int K, int RELU, int HAS_RES, int ASRC>
__global__ __launch_bounds__(256) void gemm_lds(
    const f16* __restrict__ A, const float* __restrict__ Af,
    const f16* __restrict__ Bt, const float* __restrict__ bias,
    const f16* __restrict__ R, f16* __restrict__ C, int M, int N) {
  const int tid = threadIdx.x;
  const int w = tid >> 6, lane = tid & 63;
  const int half = lane >> 5, l31 = lane & 31;
  const long bm = (long)blockIdx.x * 128;
  const int bn0 = blockIdx.y * 128;
  __shared__ u16 sA[128][72];
  __shared__ u16 sB[128][72];
  f32x16 acc[4] = {};
  for (int k0 = 0; k0 < K; k0 += 64) {
    // stage A and B tiles: 128 rows x 64 halves each; 4x256 thread-slots per tile
#pragma unroll
    for (int i = 0; i < 4; i++) {
      int c = i * 256 + tid;
      int r = c >> 3, g = c & 7;          // row 0..127, 8-half group 0..7
      long gm = bm + r; if (gm > (long)M - 1) gm = M - 1;
      if constexpr (ASRC == 0) {
        *(uint4*)&sA[r][g * 8] = *(const uint4*)(A + gm * K + k0 + g * 8);
      } else {
        float4 f0 = *(const float4*)(Af + gm * K + k0 + g * 8);
        float4 f1 = *(const float4*)(Af + gm * K + k0 + g * 8 + 4);
        hfrag h;
        h[0] = (f16)f0.x; h[1] = (f16)f0.y; h[2] = (f16)f0.z; h[3] = (f16)f0.w;
        h[4] = (f16)f1.x; h[5] = (f16)f1.y; h[6] = (f16)f1.z; h[7] = (f16)f1.w;
        *(hfrag*)&sA[r][g * 8] = h;
      }
      *(uint4*)&sB[r][g * 8] = *(const uint4*)(Bt + (long)(bn0 + r) * K + k0 + g * 8);
    }
    __syncthreads();
#pragma unroll
    for (int kk = 0; kk < 4; kk++) {
      hfrag bf = *(const hfrag*)&sB[w * 32 + l31][kk * 16 + half * 8];
#pragma unroll
      for (int i = 0; i < 4; i++) {
        hfrag af = *(const hfrag*)&sA[i * 32 + l31][kk * 16 + half * 8];
        acc[i] = MFMAH(af, bf, acc[i]);
      }
    }
    __syncthreads();
  }
  const int n = bn0 + w * 32 + l31;
  const float bi = bias ? bias[n] : 0.f;
#pragma unroll
  for (int i = 0; i < 4; i++) {
#pragma unroll
    for (int r = 0; r < 16; r++) {
      int row = (r & 3) + 8 * (r >> 2) + 4 * half;
      long gm = bm + i * 32 + row;
      if (gm < M) {
        float c = acc[i][r] + bi;
        long idx = gm * N + n;
        if constexpr (HAS_RES) c += (float)R[idx];
        if constexpr (RELU) c = fmaxf(c, 0.f);
        C[idx] = (f16)c;
      }
    }
  }
}

// LayerNorm f16 in/out, fp32 math, one row per WAVE
__global__ void ln_h(const f16* __restrict__ in, f16* __restrict__ out,
                     const float* __restrict__ g, const float* __restrict__ b, int M) {
  const int w = threadIdx.x >> 6, l = threadIdx.x & 63;
  const int r = blockIdx.x * 4 + w;
  if (r >= M) return;
  const f16* row = in + (long)r * DM;
  float v[4]; float s = 0.f, q = 0.f;
#pragma unroll
  for (int c = 0; c < 4; c++) { v[c] = (float)row[l + c * 64]; s += v[c]; q += v[c] * v[c]; }
  for (int o = 32; o; o >>= 1) { s += __shfl_xor(s, o); q += __shfl_xor(q, o); }
  float mean = s * (1.f / 256.f);
  float var = q * (1.f / 256.f) - mean * mean;
  float rs = rsqrtf(var + 1e-5f);
  f16* orow = out + (long)r * DM;
#pragma unroll
  for (int c = 0; c < 4; c++)
    orow[l + c * 64] = (f16)((v[c] - mean) * rs * g[l + c * 64] + b[l + c * 64]);
}

// dist: s[m][n] = cnorm[n] - 2*dot(kb[m], ck[n]) in fp16 MFMA.
#define DNT 32
#define DNTILES 32
template <int MODE>
__global__ __launch_bounds__(256) void mfma_dist2(
    const f16* __restrict__ Ah, const f16* __restrict__ Bh,
    const float* __restrict__ cnorm, float* __restrict__ partial,
    const float* __restrict__ minf, int* __restrict__ cnt, int* __restrict__ listI) {
  const int tid = threadIdx.x;
  const int w = tid >> 6, lane = tid & 63;
  const int half = lane >> 5, l31 = lane & 31;
  const int bm = blockIdx.x * 128;
  const long bn0 = (long)blockIdx.y * (DNT * DNTILES);
  const int STEP = (MODE == 0) ? 4 : 1;
  __shared__ u16 Bl[2][DNT][264];
  hfrag areg[16];
  {
    const hfrag* arow = (const hfrag*)(Ah + (long)(bm + w * 32 + l31) * DM);
#pragma unroll
    for (int kk = 0; kk < 16; kk++) areg[kk] = arow[kk * 2 + half];
  }
  float runmin[16], thr[16];
  if constexpr (MODE == 0) {
#pragma unroll
    for (int r = 0; r < 16; r++) runmin[r] = 3.4e38f;
  } else {
#pragma unroll
    for (int r = 0; r < 16; r++) {
      int row = (r & 3) + 8 * (r >> 2) + 4 * half;
      thr[r] = minf[bm + w * 32 + row] + DELTA;
    }
  }
#pragma unroll
  for (int i = 0; i < 4; i++) {
    int c = i * 256 + tid, row = c >> 5, col8 = c & 31;
    long gn = bn0 + row; if (gn >= NCAND) gn = NCAND - 1;
    *(uint4*)&Bl[0][row][col8 * 8] = *(const uint4*)(Bh + gn * DM + col8 * 8);
  }
  __syncthreads();
  int pi = 0;
  for (int nt = 0; nt < DNTILES; nt += STEP, pi++) {
    const int buf = pi & 1;
    uint4 v[4];
    const bool more = (nt + STEP) < DNTILES;
    if (more) {
      long base = bn0 + (long)(nt + STEP) * DNT;
#pragma unroll
      for (int i = 0; i < 4; i++) {
        int c = i * 256 + tid;
        long g = base + (c >> 5); if (g >= NCAND) g = NCAND - 1;
        v[i] = *(const uint4*)(Bh + g * DM + (c & 31) * 8);
      }
    }
    f32x16 acc0 = {}, acc1 = {};
#pragma unroll
    for (int kk = 0; kk < 16; kk += 2) {
      hfrag b0 = *(const hfrag*)&Bl[buf][l31][kk * 16 + half * 8];
      hfrag b1 = *(const hfrag*)&Bl[buf][l31][(kk + 1) * 16 + half * 8];
      acc0 = MFMAH(areg[kk], b0, acc0);
      acc1 = MFMAH(areg[kk + 1], b1, acc1);
    }
    acc0 = acc0 + acc1;
    long n = bn0 + (long)nt * DNT + l31;
    bool nok = n < NCAND;
    float cn = nok ? cnorm[n] : 0.f;
    if constexpr (MODE == 0) {
#pragma unroll
      for (int r = 0; r < 16; r++) {
        float s = nok ? cn - 2.f * acc0[r] : 3.4e38f;
        runmin[r] = fminf(runmin[r], s);
      }
    } else {
      if (nok) {
#pragma unroll
        for (int r = 0; r < 16; r++) {
          float s = cn - 2.f * acc0[r];
          if (s <= thr[r]) {
            int row = (r & 3) + 8 * (r >> 2) + 4 * half;
            int m = bm + w * 32 + row;
            int p = atomicAdd(&cnt[m], 1);
            if (p < CAP) listI[(long)m * CAP + p] = (int)n;
          }
        }
      }
    }
    if (more) {
#pragma unroll
      for (int i = 0; i < 4; i++) {
        int c = i * 256 + tid;
        *(uint4*)&Bl[buf ^ 1][c >> 5][(c & 31) * 8] = v[i];
      }
    }
    __syncthreads();
  }
  if constexpr (MODE == 0) {
#pragma unroll
    for (int r = 0; r < 16; r++) {
      float s = runmin[r];
      s = fminf(s, __shfl_xor(s, 1));  s = fminf(s, __shfl_xor(s, 2));
      s = fminf(s, __shfl_xor(s, 4));  s = fminf(s, __shfl_xor(s, 8));
      s = fminf(s, __shfl_xor(s, 16));
      if (l31 == 0) {
        int row = (r & 3) + 8 * (r >> 2) + 4 * half;
        partial[(long)blockIdx.y * B_ROWS + bm + w * 32 + row] = s;
      }
    }
  }
}

__global__ void dist_reduce(const float* __restrict__ partial, float* __restrict__ minf) {
  int m = blockIdx.x * 256 + threadIdx.x;
  float v = 3.4e38f;
  for (int j = 0; j < DNBLK; j++) v = fminf(v, partial[(long)j * B_ROWS + m]);
  minf[m] = v;
}

// LayerNorm over 256, split-bf16 planes in/out (batch path)
__global__ void ln_split(const u16* __restrict__ inh, const u16* __restrict__ inl,
                         u16* __restrict__ outh, u16* __restrict__ outl,
                         const float* __restrict__ g, const float* __restrict__ b) {
  const int r = blockIdx.x, t = threadIdx.x;
  const int w = t >> 6, l = t & 63;
  float v = dec2(inh[(long)r * DM + t], inl[(long)r * DM + t]);
  float s = v, q = v * v;
  for (int o = 32; o; o >>= 1) { s += __shfl_xor(s, o); q += __shfl_xor(q, o); }
  __shared__ float ps[4], pq[4];
  if (!l) { ps[w] = s; pq[w] = q; }
  __syncthreads();
  float S = ps[0] + ps[1] + ps[2] + ps[3];
  float Q = pq[0] + pq[1] + pq[2] + pq[3];
  float mean = S * (1.f / 256.f);
  float var = Q * (1.f / 256.f) - mean * mean;
  float rs = rsqrtf(var + 1e-5f);
  float o2 = (v - mean) * rs * g[t] + b[t];
  outh[(long)r * DM + t] = bf_hi(o2);
  outl[(long)r * DM + t] = bf_lo(o2);
}

__global__ void rownorm_h(const f16* __restrict__ X, float* __restrict__ out) {
  const int w = threadIdx.x >> 6, l = threadIdx.x & 63;
  const int r = blockIdx.x * 4 + w;
  if (r >= NCAND) return;
  const f16* row = X + (long)r * DM;
  float s = 0.f;
  for (int i = l; i < DM; i += 64) { float v = (float)row[i]; s += v * v; }
  for (int o = 32; o; o >>= 1) s += __shfl_xor(s, o);
  if (!l) out[r] = s;
}

// ||kb[r]||^2 for batch rows (fp32)
__global__ void rownorm_f(const float* __restrict__ X, float* __restrict__ out) {
  const int w = threadIdx.x >> 6, l = threadIdx.x & 63;
  const int r = blockIdx.x * 4 + w;
  if (r >= B_ROWS) return;
  const float* row = X + (long)r * DM;
  float s = 0.f;
  for (int i = l; i < DM; i += 64) { float v = row[i]; s += v * v; }
  for (int o = 32; o; o >>= 1) s += __shfl_xor(s, o);
  if (!l) out[r] = s;
}

// Tile list build: one block, 1024 threads. Tiles of 32 pairs never span rows.
__global__ void scan_tiles(const int* __restrict__ cnt, int* __restrict__ tileRow,
                           int* __restrict__ tileOff, int* __restrict__ nTiles,
                           float* __restrict__ Z, float* __restrict__ ZY) {
  const int m = threadIdx.x;
  int c = cnt[m]; if (c > CAP) c = CAP;
  int nt = (c + 31) >> 5;
  __shared__ int s[B_ROWS];
  s[m] = nt;
  __syncthreads();
  for (int off2 = 1; off2 < B_ROWS; off2 <<= 1) {
    int add = (m >= off2) ? s[m - off2] : 0;
    __syncthreads();
    s[m] += add;
    __syncthreads();
  }
  int end = s[m], base = end - nt;
  if (m == B_ROWS - 1) nTiles[0] = end;
  for (int j = 0; j < nt; j++) { tileRow[base + j] = m; tileOff[base + j] = j * 32; }
  Z[m] = 0.f; ZY[m] = 0.f;
}

// Tile-parallel values: persistent blocks stride over (row, 32-pair) tiles.
#define VT 32
__global__ __launch_bounds__(256) void values_tile(
    const float* __restrict__ Kb, const f16* __restrict__ Ck,
    const float* __restrict__ cy, const int* __restrict__ cnt,
    const int* __restrict__ listI, const float* __restrict__ minf,
    const float* __restrict__ knorm, const int* __restrict__ tileRow,
    const int* __restrict__ tileOff, const int* __restrict__ nTilesP,
    const u16* __restrict__ T1T, const float* __restrict__ Tb1,
    const u16* __restrict__ T2T,
    float* __restrict__ ctxAcc, float* __restrict__ Z, float* __restrict__ ZY) {
  const int t = threadIdx.x;
  const int w = t >> 6, lane = t & 63;
  const int half = lane >> 5, l31 = lane & 31;
  __shared__ float sk[256];
  __shared__ u16 U[VT][264];
  __shared__ u16 T1[VT][520];
  __shared__ float s2[VT], sw[VT];
  __shared__ int sidx[VT];
  __shared__ float sSW, sSWY;
  const int nTiles = nTilesP[0];
  for (int ti = blockIdx.x; ti < nTiles; ti += VGRID) {
    __syncthreads();
    const int m = tileRow[ti], j0 = tileOff[ti];
    int n = cnt[m]; if (n > CAP) n = CAP;
    const float gmin = minf[m];
    sk[t] = Kb[(long)m * DM + t];
    if (t < VT) {
      int j = j0 + t;
      sidx[t] = (j < n) ? listI[(long)m * CAP + j] : listI[(long)m * CAP];
    }
    __syncthreads();
    {
      float kc = sk[t];
#pragma unroll 4
      for (int r = 0; r < VT; r++)
        U[r][t] = f2bf_rne(kc - (float)Ck[(long)sidx[r] * DM + t]);
    }
    for (int rr = 0; rr < 8; rr++) {
      int r = w * 8 + rr;
      const f16* cr = Ck + (long)sidx[r] * DM;
      float a = 0.f;
      for (int c = lane; c < DM; c += 64) { float u = sk[c] - (float)cr[c]; a += u * u; }
      for (int o = 32; o; o >>= 1) a += __shfl_xor(a, o);
      if (!lane) s2[r] = a;
    }
    __syncthreads();
    if (w == 0) {
      float swv = 0.f, syv = 0.f;
      if (lane < VT) {
        int j = j0 + lane;
        swv = (j < n) ? expf(-(s2[lane] - knorm[m] - gmin)) : 0.f;
        syv = swv * cy[sidx[lane]];
        sw[lane] = swv;
      }
      for (int o = 16; o; o >>= 1) { swv += __shfl_xor(swv, o); syv += __shfl_xor(syv, o); }
      if (lane == 0) { sSW = swv; sSWY = syv; }
    }
    __syncthreads();
    {
      f32x16 acc[4] = {};
#pragma unroll 2
      for (int k0 = 0; k0 < DM; k0 += 16) {
        bfrag af = *(const bfrag*)&U[l31][k0 + half * 8];
#pragma unroll
        for (int nt2 = 0; nt2 < 4; nt2++) {
          int gn = w * 128 + nt2 * 32 + l31;
          bfrag bf = *(const bfrag*)&T1T[(long)gn * DM + k0 + half * 8];
          acc[nt2] = MFMAB(af, bf, acc[nt2]);
        }
      }
#pragma unroll
      for (int nt2 = 0; nt2 < 4; nt2++) {
        int gn = w * 128 + nt2 * 32 + l31;
        float bb = Tb1[gn];
#pragma unroll
        for (int r = 0; r < 16; r++) {
          int mr = (r & 3) + 8 * (r >> 2) + 4 * half;
          T1[mr][gn] = f2bf_rne(fmaxf(acc[nt2][r] + bb, 0.f));
        }
      }
    }
    __syncthreads();
    {
      f32x16 acc[2] = {};
#pragma unroll 2
      for (int k0 = 0; k0 < DBK; k0 += 16) {
        bfrag af = *(const bfrag*)&T1[l31][k0 + half * 8];
#pragma unroll
        for (int nt2 = 0; nt2 < 2; nt2++) {
          int gn = w * 64 + nt2 * 32 + l31;
          bfrag bf = *(const bfrag*)&T2T[(long)gn * DBK + k0 + half * 8];
          acc[nt2] = MFMAB(af, bf, acc[nt2]);
        }
      }
      float swr[16];
#pragma unroll
      for (int r = 0; r < 16; r++) swr[r] = sw[(r & 3) + 8 * (r >> 2) + 4 * half];
#pragma unroll
      for (int nt2 = 0; nt2 < 2; nt2++) {
        int gn = w * 64 + nt2 * 32 + l31;
        float p = 0.f;
#pragma unroll
        for (int r = 0; r < 16; r++) p += swr[r] * acc[nt2][r];
        p += __shfl_xor(p, 32);
        if (half == 0) atomicAdd(&ctxAcc[(long)m * DM + gn], p);
      }
      if (t == 0) { atomicAdd(&Z[m], sSW); atomicAdd(&ZY[m], sSWY); }
    }
  }
}

// x=xb+(ctxAcc+ZY*labw+Z*labb)/Z; x+=MLP(LN(x)); out=relu(LN(x))@hw+hb2. 4 rows/block.
__global__ void final_kernel(const float* __restrict__ xb, const float* __restrict__ ctxAcc,
                             const float* __restrict__ Z, const float* __restrict__ ZY,
                             const float* __restrict__ labw, const float* __restrict__ labb,
                             const float* __restrict__ pg, const float* __restrict__ pb,
                             const float* __restrict__ pw1, const float* __restrict__ pb1,
                             const float* __restrict__ pw2, const float* __restrict__ pb2,
                             const float* __restrict__ hg, const float* __restrict__ hb,
                             const float* __restrict__ hw, const float* __restrict__ hb2,
                             float* __restrict__ out) {
  const int b0 = blockIdx.x * 4, t = threadIdx.x;
  const int w = t >> 6, l = t & 63;
  __shared__ float sx[4][260], sln[4][260], sh[4][516], sx2[4][260];
  for (int e = t; e < 1024; e += 256) {
    int r = e >> 8, d = e & 255;
    int m = b0 + r;
    float zi = 1.f / Z[m];
    float ctx = (ctxAcc[(long)m * DM + d] + ZY[m] * labw[d] + Z[m] * labb[d]) * zi;
    sx[r][d] = xb[(long)m * DM + d] + ctx;
  }
  __syncthreads();
  {
    float s = 0.f, q = 0.f;
    for (int d = l; d < 256; d += 64) { float v = sx[w][d]; s += v; q += v * v; }
    for (int o = 32; o; o >>= 1) { s += __shfl_xor(s, o); q += __shfl_xor(q, o); }
    float mean = s * (1.f / 256.f), var = q * (1.f / 256.f) - mean * mean;
    float rs = rsqrtf(var + 1e-5f);
    for (int d = l; d < 256; d += 64) sln[w][d] = (sx[w][d] - mean) * rs * pg[d] + pb[d];
  }
  __syncthreads();
  {
    float acc[4][2] = {};
    for (int k = 0; k < 256; k++) {
      float w0 = pw1[(long)k * DBK + t], w1 = pw1[(long)k * DBK + t + 256];
#pragma unroll
      for (int r = 0; r < 4; r++) { float a = sln[r][k]; acc[r][0] += a * w0; acc[r][1] += a * w1; }
    }
#pragma unroll
    for (int r = 0; r < 4; r++) {
      sh[r][t] = fmaxf(acc[r][0] + pb1[t], 0.f);
      sh[r][t + 256] = fmaxf(acc[r][1] + pb1[t + 256], 0.f);
    }
  }
  __syncthreads();
  {
    float acc2[4] = {};
    for (int k = 0; k < 512; k++) {
      float wv = pw2[(long)k * DM + t];
#pragma unroll
      for (int r = 0; r < 4; r++) acc2[r] += sh[r][k] * wv;
    }
#pragma unroll
    for (int r = 0; r < 4; r++) sx2[r][t] = sx[r][t] + acc2[r] + pb2[t];
  }
  __syncthreads();
  {
    float s = 0.f, q = 0.f;
    for (int d = l; d < 256; d += 64) { float v = sx2[w][d]; s += v; q += v * v; }
    for (int o = 32; o; o >>= 1) { s += __shfl_xor(s, o); q += __shfl_xor(q, o); }
    float mean = s * (1.f / 256.f), var = q * (1.f / 256.f) - mean * mean;
    float rs = rsqrtf(var + 1e-5f);
    float dp = 0.f;
    for (int d = l; d < 256; d += 64) {
      float v = fmaxf((sx2[w][d] - mean) * rs * hg[d] + hb[d], 0.f);
      dp += v * hw[d];
    }
    for (int o = 32; o; o >>= 1) dp += __shfl_xor(dp, o);
    if (!l) out[b0 + w] = dp + hb2[0];
  }
}

extern "C" void kernel_launch(void* const* d_in, const int* in_sizes, int n_in,
                              void* d_out, int out_size, void* d_ws, size_t ws_size,
                              hipStream_t stream) {
  const float* x_num = (const float*)d_in[0];
  const float* cand  = (const float*)d_in[1];
  const float* cy    = (const float*)d_in[2];
  const float* lin_w = (const float*)d_in[4];
  const float* lin_b = (const float*)d_in[5];
  const float* b0w1  = (const float*)d_in[6];
  const float* b0b1  = (const float*)d_in[7];
  const float* b0w2  = (const float*)d_in[8];
  const float* b0b2  = (const float*)d_in[9];
  const float* mixg  = (const float*)d_in[10];
  const float* mixb  = (const float*)d_in[11];
  const float* Kw    = (const float*)d_in[12];
  const float* Kbias = (const float*)d_in[13];
  const float* labw  = (const float*)d_in[14];
  const float* labb  = (const float*)d_in[15];
  const float* Tw1   = (const float*)d_in[16];
  const float* Tb1   = (const float*)d_in[17];
  const float* Tw2   = (const float*)d_in[18];
  const float* pg    = (const float*)d_in[19];
  const float* pb    = (const float*)d_in[20];
  const float* pw1   = (const float*)d_in[21];
  const float* pb1   = (const float*)d_in[22];
  const float* pw2   = (const float*)d_in[23];
  const float* pb2   = (const float*)d_in[24];
  const float* hg    = (const float*)d_in[25];
  const float* hb    = (const float*)d_in[26];
  const float* hw    = (const float*)d_in[27];
  const float* hb2   = (const float*)d_in[28];
  float* out = (float*)d_out;

  char* ws = (char*)d_ws;
  size_t off = 0;
  auto alloc = [&](size_t bytes) -> void* {
    void* p = ws + off;
    off += (bytes + 255) & ~(size_t)255;
    return p;
  };
  f16*   ck_h    = (f16*)alloc((size_t)NCAND * DM * 2);
  float* cnorm   = (float*)alloc((size_t)NCAND * 4);
  float* partial = (float*)alloc((size_t)DNBLK * B_ROWS * 4);
  float* minf    = (float*)alloc((size_t)B_ROWS * 4);
  int*   cnt     = (int*)alloc((size_t)B_ROWS * 4);
  int*   listI   = (int*)alloc((size_t)B_ROWS * CAP * 4);
  float* xb      = (float*)alloc((size_t)B_ROWS * DM * 4);
  float* kb      = (float*)alloc((size_t)B_ROWS * DM * 4);
  f16*   kb_h    = (f16*)alloc((size_t)B_ROWS * DM * 2);
  float* ctxAcc  = (float*)alloc((size_t)B_ROWS * DM * 4);
  float* Z       = (float*)alloc((size_t)B_ROWS * 4);
  float* ZY      = (float*)alloc((size_t)B_ROWS * 4);
  float* knorm   = (float*)alloc((size_t)B_ROWS * 4);
  int*   tileRow = (int*)alloc((size_t)B_ROWS * 32 * 4);
  int*   tileOff = (int*)alloc((size_t)B_ROWS * 32 * 4);
  int*   nTiles  = (int*)alloc(256);
  u16* bx1h = (u16*)alloc((size_t)B_ROWS * DM * 2);
  u16* bx1l = (u16*)alloc((size_t)B_ROWS * DM * 2);
  u16* bhh  = (u16*)alloc((size_t)B_ROWS * DBK * 2);
  u16* bhl  = (u16*)alloc((size_t)B_ROWS * DBK * 2);
  u16* bx2h = (u16*)alloc((size_t)B_ROWS * DM * 2);
  u16* bx2l = (u16*)alloc((size_t)B_ROWS * DM * 2);
  u16* blnh = (u16*)alloc((size_t)B_ROWS * DM * 2);
  u16* blnl = (u16*)alloc((size_t)B_ROWS * DM * 2);
  u16* linTh = (u16*)alloc((size_t)DM * DIN * 2);
  u16* linTl = (u16*)alloc((size_t)DM * DIN * 2);
  u16* w1Th  = (u16*)alloc((size_t)DBK * DM * 2);
  u16* w1Tl  = (u16*)alloc((size_t)DBK * DM * 2);
  u16* w2Th  = (u16*)alloc((size_t)DM * DBK * 2);
  u16* w2Tl  = (u16*)alloc((size_t)DM * DBK * 2);
  u16* KwTh  = (u16*)alloc((size_t)DM * DM * 2);
  u16* KwTl  = (u16*)alloc((size_t)DM * DM * 2);
  u16* T1T   = (u16*)alloc((size_t)DBK * DM * 2);
  u16* T2T   = (u16*)alloc((size_t)DM * DBK * 2);
  f16* linH  = (f16*)alloc((size_t)DM * DIN * 2);
  f16* w1H   = (f16*)alloc((size_t)DBK * DM * 2);
  f16* w2H   = (f16*)alloc((size_t)DM * DBK * 2);
  f16* KwH   = (f16*)alloc((size_t)DM * DM * 2);
  size_t fixed_end = off;
  long chunk = 0;
  if (ws_size > fixed_end + 8192) {
    chunk = (long)((ws_size - fixed_end - 8192) / 2048);
    chunk -= chunk % 128;
    if (chunk > 100352) chunk = 100352;
  }
  if (chunk < 128) {
    diag_kernel<<<dim3(4), dim3(256), 0, stream>>>(out, (float)(ws_size >> 20));
    return;
  }
  f16* cx1 = (f16*)alloc((size_t)chunk * DM * 2);
  f16* chb = (f16*)alloc((size_t)chunk * DBK * 2);
  f16* cx2 = (f16*)alloc((size_t)chunk * DM * 2);

  prep_weights<<<dim3((unsigned)((SEG0+SEG1+SEG2+SEG3+SEG4+SEG5+SEG6+SEG7+SEG8+SEG9 + 255) / 256)),
                 dim3(256), 0, stream>>>(
      lin_w, b0w1, b0w2, Kw, Tw1, Tw2, linTh, linTl, w1Th, w1Tl, w2Th, w2Tl, KwTh, KwTl,
      T1T, T2T, linH, w1H, w2H, KwH);
  init_kernel<<<dim3(4), dim3(256), 0, stream>>>(cnt);
  zero_f<<<dim3(B_ROWS), dim3(256), 0, stream>>>(ctxAcc);

  // ---- batch encode (split-bf16 precision path) ----
  mfma_nt<0,0,1,1,0,0><<<dim3(8, 2), dim3(256), 0, stream>>>(
      nullptr, nullptr, x_num, linTh, linTl, lin_b, nullptr, nullptr,
      bx1h, bx1l, nullptr, nullptr, B_ROWS, DIN, DM);
  mfma_nt<1,0,0,1,0,0><<<dim3(8, 4), dim3(256), 0, stream>>>(
      bx1h, bx1l, nullptr, w1Th, w1Tl, b0b1, nullptr, nullptr,
      bhh, bhl, nullptr, nullptr, B_ROWS, DM, DBK);
  mfma_nt<0,1,0,1,1,0><<<dim3(8, 2), dim3(256), 0, stream>>>(
      bhh, bhl, nullptr, w2Th, w2Tl, b0b2, bx1h, bx1l,
      bx2h, bx2l, xb, nullptr, B_ROWS, DBK, DM);
  ln_split<<<dim3(B_ROWS), dim3(256), 0, stream>>>(bx2h, bx2l, blnh, blnl, mixg, mixb);
  mfma_nt<0,0,0,0,1,1><<<dim3(8, 2), dim3(256), 0, stream>>>(
      blnh, blnl, nullptr, KwTh, KwTl, Kbias, nullptr, nullptr,
      nullptr, nullptr, kb, kb_h, B_ROWS, DM, DM);
  rownorm_f<<<dim3(B_ROWS / 4), dim3(256), 0, stream>>>(kb, knorm);

  // ---- candidate encode (LDS-tiled f16 GEMMs) ----
  for (long o = 0; o < NCAND; o += chunk) {
    long m = NCAND - o; if (m > chunk) m = chunk;
    unsigned gx = (unsigned)((m + 127) / 128);
    gemm_lds<128,0,0,1><<<dim3(gx, 2), dim3(256), 0, stream>>>(
        nullptr, cand + o * DIN, linH, lin_b, nullptr, cx1, (int)m, DM);
    gemm_lds<256,1,0,0><<<dim3(gx, 4), dim3(256), 0, stream>>>(
        cx1, nullptr, w1H, b0b1, nullptr, chb, (int)m, DBK);
    gemm_lds<512,0,1,0><<<dim3(gx, 2), dim3(256), 0, stream>>>(
        chb, nullptr, w2H, b0b2, cx1, cx2, (int)m, DM);
    ln_h<<<dim3((unsigned)((m + 3) / 4)), dim3(256), 0, stream>>>(cx2, cx1, mixg, mixb, (int)m);
    gemm_lds<256,0,0,0><<<dim3(gx, 2), dim3(256), 0, stream>>>(
        cx1, nullptr, KwH, Kbias, nullptr, ck_h + o * DM, (int)m, DM);
  }
  rownorm_h<<<dim3(NCAND / 4), dim3(256), 0, stream>>>(ck_h, cnorm);

  // ---- neighbor window: sampled-min pass -> reduce -> compact pass ----
  mfma_dist2<0><<<dim3(8, DNBLK), dim3(256), 0, stream>>>(kb_h, ck_h, cnorm, partial, nullptr, nullptr, nullptr);
  dist_reduce<<<dim3(4), dim3(256), 0, stream>>>(partial, minf);
  mfma_dist2<1><<<dim3(8, DNBLK), dim3(256), 0, stream>>>(kb_h, ck_h, cnorm, nullptr, minf, cnt, listI);

  // ---- tile list + tile-parallel values ----
  scan_tiles<<<dim3(1), dim3(B_ROWS), 0, stream>>>(cnt, tileRow, tileOff, nTiles, Z, ZY);
  values_tile<<<dim3(VGRID), dim3(256), 0, stream>>>(kb, ck_h, cy, cnt, listI, minf, knorm,
                                                     tileRow, tileOff, nTiles,
                                                     T1T, Tb1, T2T, ctxAcc, Z, ZY);
  // ---- residual MLP + head ----
  final_kernel<<<dim3(B_ROWS / 4), dim3(256), 0, stream>>>(xb, ctxAcc, Z, ZY, labw, labb,
                                                           pg, pb, pw1, pb1, pw2, pb2,
                                                           hg, hb, hw, hb2, out);
}